// Round 6
// baseline (9011.703 us; speedup 1.0000x reference)
//
#include <hip/hip_runtime.h>
#include <stdint.h>

typedef _Float16 f16;
typedef _Float16 f16x8 __attribute__((ext_vector_type(8)));
typedef float f32x4 __attribute__((ext_vector_type(4)));
typedef uint32_t u32;

#define SEQ 8192
#define NH 16
#define HDIM 128
#define BHCNT 32
#define KDIM 2048
#define SCALE 0.08838834764831845f
#define LOGW 3.4657359027997265f
#define TAU 6e-3f
#define MAXWL 32768
#define NEGF -3.402823466e38f

__device__ __forceinline__ f32x4 mfma16(f16x8 a, f16x8 b, f32x4 c){
  return __builtin_amdgcn_mfma_f32_16x16x32_f16(a, b, c, 0, 0, 0);
}

__device__ __forceinline__ void g2l16(const f16* g, f16* l){
  __builtin_amdgcn_global_load_lds(
      (const __attribute__((address_space(1))) void*)g,
      (__attribute__((address_space(3))) void*)l, 16, 0, 0);
}

// ---------- prep: x -> hi/lo fp16 ----------
__global__ __launch_bounds__(256) void split_x_k(const float* __restrict__ x,
                                                 f16* __restrict__ xh, f16* __restrict__ xl){
  size_t i = ((size_t)blockIdx.x * 256 + threadIdx.x) * 4;
  float4 v = *(const float4*)(x + i);
  f16 h0 = (f16)v.x, h1 = (f16)v.y, h2 = (f16)v.z, h3 = (f16)v.w;
  union { f16 h[4]; ushort4 u; } a, b;
  a.h[0]=h0; a.h[1]=h1; a.h[2]=h2; a.h[3]=h3;
  b.h[0]=(f16)(v.x-(float)h0); b.h[1]=(f16)(v.y-(float)h1);
  b.h[2]=(f16)(v.z-(float)h2); b.h[3]=(f16)(v.w-(float)h3);
  *(ushort4*)(xh + i) = a.u;
  *(ushort4*)(xl + i) = b.u;
}

// ---------- prep: transpose+convert weights (in [Kd][Nd] -> out [Nd][Kd]) ----------
__global__ void transpose_k(const float* __restrict__ in, f16* __restrict__ ohi,
                            f16* __restrict__ olo, int Kd, int Nd, int NLO){
  __shared__ float t[32][33];
  int tx = threadIdx.x, ty = threadIdx.y;
  int n0 = blockIdx.x*32, k0 = blockIdx.y*32;
  #pragma unroll
  for (int i=0;i<4;i++) t[ty+i*8][tx] = in[(size_t)(k0+ty+i*8)*Nd + n0+tx];
  __syncthreads();
  #pragma unroll
  for (int i=0;i<4;i++){
    int n = n0 + ty + i*8, k = k0 + tx;
    float v = t[tx][ty+i*8];
    f16 h = (f16)v;
    ohi[(size_t)n*Kd + k] = h;
    if (n < NLO) olo[(size_t)n*Kd + k] = (f16)(v - (float)h);
  }
}

// ---------- prep: rope cos/sin table ----------
// Mimic numpy exactly: inv = f32_div(1.0f, f32(10000.0 ^ (d/64)))  (TWO f32 roundings),
// freqs = f32(s) * inv (f32 mult), trig of that f32 angle.
__global__ __launch_bounds__(256) void rope_table_k(float* __restrict__ ct, float* __restrict__ st){
  int i = blockIdx.x * 256 + threadIdx.x;
  int s = i >> 6, d = i & 63;
  float p32 = (float)pow(10000.0, (double)d / 64.0);  // f32(10000^e), correctly rounded
  float inv = __fdiv_rn(1.0f, p32);                   // second f32 rounding (numpy's 1.0/x)
  float f = __fmul_rn((float)s, inv);                 // f32 product, as numpy
  double a = (double)f;
  ct[i] = (float)cos(a);
  st[i] = (float)sin(a);
}

__global__ void zero_k(int* p){ *p = 0; }

// ---------- diagnostic: only fires if flagging machinery is broken ----------
__global__ void diag_k(const int* __restrict__ wcnt, float* __restrict__ out){
  int c = *wcnt;
  if (c == 0 || c >= MAXWL) out[0] = 1.0e9f + (float)c;
}

// ---------- GEMM: A[M][K] * Bt[N][K]^T. MODE 0: fp32 row-major out. 1: q/k fp32 strided. 2: v f16 strided ----------
template<int SPLIT, int MODE>
__global__ __launch_bounds__(256) void gemm_k(
    const f16* __restrict__ A, const f16* __restrict__ Al,
    const f16* __restrict__ Bt, const f16* __restrict__ Btl,
    float* __restrict__ o0, float* __restrict__ o1, f16* __restrict__ oh, int N){
  __shared__ f16 sm[SPLIT ? 16384 : 8192];
  const int tid = threadIdx.x, lane = tid & 63, wave = tid >> 6;
  const int wr = wave >> 1, wc = wave & 1;
  const int brow = blockIdx.y, bcol = blockIdx.x;
  f32x4 acc[4][4];
  #pragma unroll
  for (int m=0;m<4;m++)
    #pragma unroll
    for (int n=0;n<4;n++) acc[m][n] = (f32x4){0.f,0.f,0.f,0.f};
  const int srow = tid >> 2, scol = (tid & 3) * 8;
  const f16* ga0 = A  + (size_t)(brow*128 + srow)*KDIM + scol;
  const f16* gb0 = Bt + (size_t)(bcol*128 + srow)*KDIM + scol;
  f16* As = sm; f16* Bs = sm + 4096;
  f16* dA0 = As + wave*512; f16* dA1 = As + 2048 + wave*512;
  f16* dB0 = Bs + wave*512; f16* dB1 = Bs + 2048 + wave*512;
  const int aoff = (wr*64 + (lane & 15))*32 + (lane>>4)*8;
  const int boff = (wc*64 + (lane & 15))*32 + (lane>>4)*8;
  for (int kt = 0; kt < KDIM/32; ++kt){
    const size_t ko = (size_t)kt * 32;
    g2l16(ga0 + ko, dA0); g2l16(ga0 + (size_t)64*KDIM + ko, dA1);
    g2l16(gb0 + ko, dB0); g2l16(gb0 + (size_t)64*KDIM + ko, dB1);
    if constexpr (SPLIT){
      const f16* gal = Al  + (ga0 - A);
      const f16* gbl = Btl + (gb0 - Bt);
      g2l16(gal + ko, sm + 8192  + wave*512); g2l16(gal + (size_t)64*KDIM + ko, sm + 8192  + 2048 + wave*512);
      g2l16(gbl + ko, sm + 12288 + wave*512); g2l16(gbl + (size_t)64*KDIM + ko, sm + 12288 + 2048 + wave*512);
    }
    __syncthreads();
    f16x8 af[4], afl[4];
    #pragma unroll
    for (int m=0;m<4;m++){
      af[m] = *(const f16x8*)&As[aoff + m*16*32];
      if constexpr (SPLIT) afl[m] = *(const f16x8*)&sm[8192 + aoff + m*16*32];
    }
    #pragma unroll
    for (int n=0;n<4;n++){
      f16x8 bf = *(const f16x8*)&Bs[boff + n*16*32];
      f16x8 bfl;
      if constexpr (SPLIT) bfl = *(const f16x8*)&sm[12288 + boff + n*16*32];
      #pragma unroll
      for (int m=0;m<4;m++){
        acc[m][n] = mfma16(af[m], bf, acc[m][n]);
        if constexpr (SPLIT){
          acc[m][n] = mfma16(af[m],  bfl, acc[m][n]);
          acc[m][n] = mfma16(afl[m], bf,  acc[m][n]);
        }
      }
    }
    __syncthreads();
  }
  const int g = lane >> 4, q_ = lane & 15;
  #pragma unroll
  for (int m=0;m<4;m++)
    #pragma unroll
    for (int n=0;n<4;n++)
      #pragma unroll
      for (int j=0;j<4;j++){
        int row = brow*128 + wr*64 + m*16 + g*4 + j;
        int col = bcol*128 + wc*64 + n*16 + q_;
        float v = acc[m][n][j];
        if constexpr (MODE == 0){
          o0[(size_t)row * N + col] = v;
        } else if constexpr (MODE == 1){
          int b = row >> 13, s = row & 8191;
          int cl = col & 2047;
          int h = cl >> 7, hd = cl & 127;
          float* dst = (col < 2048) ? o0 : o1;
          dst[(((size_t)b*NH + h)*SEQ + s)*HDIM + hd] = v;
        } else {
          int b = row >> 13, s = row & 8191;
          int h = col >> 7, hd = col & 127;
          oh[(((size_t)b*NH + h)*SEQ + s)*HDIM + hd] = (f16)v;
        }
      }
}

// ---------- rope (fp32, in-place f16 overwrite) + LSH hash + near-zero flagging ----------
__global__ __launch_bounds__(256) void rope_hash_k(float* __restrict__ qk, const float* __restrict__ ct,
    const float* __restrict__ st, const float* __restrict__ proj, int* __restrict__ hout,
    int tag, int* __restrict__ wl, int* __restrict__ wcnt){
  const int lane = threadIdx.x & 63, wave = threadIdx.x >> 6;
  const int s = blockIdx.x * 4 + wave, bh = blockIdx.y;
  float* row = qk + ((size_t)bh * SEQ + s) * HDIM;
  float2 v = *(const float2*)(row + 2*lane);
  float ox = __shfl_xor(v.x, 32), oy = __shfl_xor(v.y, 32);
  const int dl = 2*lane, di = dl & 63;
  const float* cb = ct + (size_t)s*64; const float* sb = st + (size_t)s*64;
  float c0 = cb[di], c1 = cb[di+1], sn0 = sb[di], sn1 = sb[di+1];
  float r0, r1;
  if (lane < 32){ r0 = v.x*c0 - ox*sn0; r1 = v.y*c1 - oy*sn1; }
  else          { r0 = v.x*c0 + ox*sn0; r1 = v.y*c1 + oy*sn1; }
  union { f16 h[2]; u32 u; } pk;
  pk.h[0] = (f16)r0; pk.h[1] = (f16)r1;
  *(u32*)((f16*)row + dl) = pk.u;   // in-place: 128 f16 in first 256B of the 512B row
  float part[7];
  #pragma unroll
  for (int p=0;p<7;p++) part[p] = r0*proj[dl*7+p] + r1*proj[(dl+1)*7+p];
  #pragma unroll
  for (int off=32; off>=1; off>>=1){
    #pragma unroll
    for (int p=0;p<7;p++) part[p] += __shfl_xor(part[p], off);
  }
  if (lane == 0){
    int hs = 0; float mn = 1e30f;
    #pragma unroll
    for (int p=0;p<7;p++){ if (part[p] > 0.f) hs |= (1<<p); mn = fminf(mn, fabsf(part[p])); }
    hout[bh*SEQ + s] = hs;
    if (mn < TAU){
      int w = atomicAdd(wcnt, 1);
      if (w < MAXWL){ wl[2*w] = (bh<<1) | tag; wl[2*w+1] = s; }
    }
  }
}

// ---------- exact-f64 GEMM hash recompute for flagged rows, using the corrected f32 table ----------
__global__ __launch_bounds__(256) void fixup_k(const float* __restrict__ x, const float* __restrict__ w_in,
    const float* __restrict__ proj, const float* __restrict__ ct, const float* __restrict__ st,
    const int* __restrict__ wl, const int* __restrict__ wcnt,
    int* __restrict__ hq, int* __restrict__ hk){
  const int lane = threadIdx.x & 63, wave = threadIdx.x >> 6;
  const int gw = blockIdx.x * 4 + wave, nw = gridDim.x * 4;
  int count = *wcnt; if (count > MAXWL) count = MAXWL;
  for (int e = gw; e < count; e += nw){
    int tagbh = wl[2*e], s = wl[2*e+1];
    int tag = tagbh & 1, bh = tagbh >> 1;
    int b = bh >> 4, h = bh & 15;
    const float* xr = x + ((size_t)b*SEQ + s)*KDIM;
    const int c0i = tag*2048 + h*128 + lane;
    double a0 = 0.0, a1 = 0.0;
    for (int j = 0; j < KDIM; ++j){
      double xv = (double)xr[j];
      a0 += xv * (double)w_in[(size_t)j*6144 + c0i];
      a1 += xv * (double)w_in[(size_t)j*6144 + c0i + 64];
    }
    // rope with the SAME corrected f32 table (promoted to f64)
    double c = (double)ct[(size_t)s*64 + lane];
    double sn = (double)st[(size_t)s*64 + lane];
    double r0 = a0*c - a1*sn;
    double r1 = a1*c + a0*sn;
    int hs = 0;
    #pragma unroll
    for (int p = 0; p < 7; ++p){
      double part = r0 * (double)proj[lane*7+p] + r1 * (double)proj[(lane+64)*7+p];
      #pragma unroll
      for (int off = 32; off >= 1; off >>= 1) part += __shfl_xor(part, off);
      if (part > 0.0) hs |= (1<<p);
    }
    if (lane == 0) (tag ? hk : hq)[bh*SEQ + s] = hs;
  }
}

// ---------- stable counting sort by hash (128 bins), one block per (b,h) ----------
__global__ __launch_bounds__(128) void sort_k(const int* __restrict__ hsh, int* __restrict__ idx){
  const int bh = blockIdx.x, tid = threadIdx.x;
  __shared__ unsigned char hl[SEQ];
  __shared__ int cnt[129];
  const int* hrow = hsh + bh*SEQ;
  for (int i = tid; i < SEQ; i += 128) hl[i] = (unsigned char)hrow[i];
  __syncthreads();
  int c = 0;
  for (int i = 0; i < SEQ; ++i) c += (hl[i] == tid) ? 1 : 0;
  cnt[tid+1] = c;
  __syncthreads();
  if (tid == 0){
    cnt[0] = 0;
    for (int v2 = 1; v2 <= 128; ++v2) cnt[v2] += cnt[v2-1];
  }
  __syncthreads();
  int pos = cnt[tid];
  int* orow = idx + bh*SEQ;
  for (int i = 0; i < SEQ; ++i) if (hl[i] == tid) orow[pos++] = i;
}

// ---------- NAIVE attention: literal transcription of the reference per sorted q-row ----------
__global__ __launch_bounds__(256) void attn_naive_k(const f16* __restrict__ qr, const f16* __restrict__ kr,
    const f16* __restrict__ v, const int* __restrict__ qidx, const int* __restrict__ kidx,
    const int* __restrict__ smp, f16* __restrict__ out){
  const int p = blockIdx.x, bh = blockIdx.y;
  const int b = bh >> 4, h = bh & 15;
  const int tid = threadIdx.x;
  const int qblock = p >> 8;
  __shared__ float qs[128];
  __shared__ float sc[512];
  __shared__ float pw[512];
  __shared__ int   kid[512];
  __shared__ float red[256];
  __shared__ float lsev[2];
  const int qi = qidx[bh*SEQ + p];
  const f16* qrow = qr + ((size_t)bh*SEQ + qi)*256;
  if (tid < 128) qs[tid] = (float)qrow[tid];
  for (int kk = tid; kk < 512; kk += 256){
    int kpos;
    int mask = 0;
    if (kk < 256) kpos = qblock*256 + kk;
    else { kpos = smp[bh*256 + (kk-256)]; if ((kpos >> 8) == qblock) mask = 1; }
    kid[kk] = kidx[bh*SEQ + kpos] | (mask << 30);
  }
  __syncthreads();
  for (int kk = tid; kk < 512; kk += 256){
    int ki = kid[kk];
    int mask = (ki >> 30) & 1;
    ki &= 0x3FFFFFFF;
    const f16* krow = kr + ((size_t)bh*SEQ + ki)*256;
    float acc = 0.f;
    for (int d = 0; d < 128; ++d) acc += qs[d] * (float)krow[d];
    float s = acc * SCALE;
    if (mask) s = s + NEGF;
    sc[kk] = s;
  }
  __syncthreads();
  for (int half = 0; half < 2; ++half){
    red[tid] = sc[half*256 + tid];
    __syncthreads();
    for (int st = 128; st >= 1; st >>= 1){
      if (tid < st) red[tid] = fmaxf(red[tid], red[tid+st]);
      __syncthreads();
    }
    float m = red[0];
    __syncthreads();
    red[tid] = expf(sc[half*256 + tid] - m);
    __syncthreads();
    for (int st = 128; st >= 1; st >>= 1){
      if (tid < st) red[tid] = red[tid] + red[tid+st];
      __syncthreads();
    }
    if (tid == 0) lsev[half] = m + logf(red[0]);
    __syncthreads();
  }
  const float lse_blk = lsev[0], lse_res0 = lsev[1];
  for (int kk = tid; kk < 512; kk += 256){
    float lse = (kk < 256) ? lse_blk : lse_res0;
    pw[kk] = expf(sc[kk] - lse);
  }
  __syncthreads();
  if (tid < 128){
    const int d = tid;
    float ablk = 0.f, ares = 0.f;
    for (int j = 0; j < 256; ++j){
      int ki = kid[j] & 0x3FFFFFFF;
      ablk += pw[j] * (float)v[((size_t)bh*SEQ + ki)*HDIM + d];
    }
    for (int j = 256; j < 512; ++j){
      int ki = kid[j] & 0x3FFFFFFF;
      ares += pw[j] * (float)v[((size_t)bh*SEQ + ki)*HDIM + d];
    }
    float lse_res = lse_res0 + LOGW;
    float M = fmaxf(lse_blk, lse_res);
    float lse = M + logf(expf(lse_blk - M) + expf(lse_res - M));
    float o = ablk * expf(lse_blk - lse) + ares * expf(lse_res - lse);
    out[(((size_t)b*SEQ + qi)*NH + h)*HDIM + d] = (f16)o;
  }
}

extern "C" void kernel_launch(void* const* d_in, const int* in_sizes, int n_in,
                              void* d_out, int out_size, void* d_ws, size_t ws_size,
                              hipStream_t stream) {
  (void)in_sizes; (void)n_in; (void)out_size; (void)ws_size;
  const float* x     = (const float*)d_in[0];
  const float* w_in  = (const float*)d_in[1];
  const float* w_out = (const float*)d_in[2];
  const float* proj  = (const float*)d_in[3];
  const int*   smp   = (const int*)d_in[4];
  float* out = (float*)d_out;

  char* ws = (char*)d_ws;
  size_t off = 0;
  auto alloc = [&](size_t bytes){ void* p = ws + off; off += (bytes + 255) & ~(size_t)255; return p; };
  f16*   xh   = (f16*)alloc((size_t)16384*2048*2);
  f16*   xl   = (f16*)alloc((size_t)16384*2048*2);
  f16*   wh   = (f16*)alloc((size_t)6144*2048*2);
  f16*   wl   = (f16*)alloc((size_t)4096*2048*2);
  f16*   wo   = (f16*)alloc((size_t)2048*2048*2);
  float* qf   = (float*)alloc((size_t)BHCNT*SEQ*HDIM*4);
  float* kf   = (float*)alloc((size_t)BHCNT*SEQ*HDIM*4);
  f16*   vv   = (f16*)alloc((size_t)BHCNT*SEQ*HDIM*2);
  float* cost = (float*)alloc((size_t)SEQ*64*4);
  float* sint = (float*)alloc((size_t)SEQ*64*4);
  int*   hq   = (int*)alloc((size_t)BHCNT*SEQ*4);
  int*   hk   = (int*)alloc((size_t)BHCNT*SEQ*4);
  int*   qidx = (int*)alloc((size_t)BHCNT*SEQ*4);
  int*   kidx = (int*)alloc((size_t)BHCNT*SEQ*4);
  int*   wlst = (int*)alloc((size_t)MAXWL*2*4);
  int*   wcnt = (int*)alloc(256);
  f16*   attn = xl;   // xl is dead after the split GEMM; reuse as attention output

  zero_k<<<1, 1, 0, stream>>>(wcnt);
  split_x_k<<<32768, 256, 0, stream>>>(x, xh, xl);
  transpose_k<<<dim3(192,64), dim3(32,8), 0, stream>>>(w_in, wh, wl, 2048, 6144, 4096);
  transpose_k<<<dim3(64,64),  dim3(32,8), 0, stream>>>(w_out, wo, nullptr, 2048, 2048, 0);
  rope_table_k<<<2048, 256, 0, stream>>>(cost, sint);

  gemm_k<1,1><<<dim3(32,128), 256, 0, stream>>>(xh, xl, wh, wl, qf, kf, nullptr, 4096);
  gemm_k<0,2><<<dim3(16,128), 256, 0, stream>>>(xh, nullptr, wh + (size_t)4096*2048, nullptr,
                                                nullptr, nullptr, vv, 2048);

  rope_hash_k<<<dim3(2048,32), 256, 0, stream>>>(qf, cost, sint, proj, hq, 0, wlst, wcnt);
  rope_hash_k<<<dim3(2048,32), 256, 0, stream>>>(kf, cost, sint, proj, hk, 1, wlst, wcnt);

  // exact-f64 recompute of near-zero hash decisions (corrected f32 table)
  fixup_k<<<512, 256, 0, stream>>>(x, w_in, proj, cost, sint, wlst, wcnt, hq, hk);

  sort_k<<<32, 128, 0, stream>>>(hq, qidx);
  sort_k<<<32, 128, 0, stream>>>(hk, kidx);

  attn_naive_k<<<dim3(8192,32), 256, 0, stream>>>((const f16*)qf, (const f16*)kf, vv,
                                                  qidx, kidx, smp, attn);

  gemm_k<0,0><<<dim3(16,128), 256, 0, stream>>>(attn, nullptr, wo, nullptr,
                                                out, nullptr, nullptr, 2048);

  // nominal-silent diagnostic: fires only if the flagging machinery is broken
  diag_k<<<1, 1, 0, stream>>>(wcnt, out);
}

// Round 7
// 3284.508 us; speedup vs baseline: 2.7437x; 2.7437x over previous
//
#include <hip/hip_runtime.h>
#include <stdint.h>

typedef _Float16 f16;
typedef _Float16 f16x8 __attribute__((ext_vector_type(8)));
typedef float f32x4 __attribute__((ext_vector_type(4)));
typedef uint32_t u32;

#define SEQ 8192
#define NH 16
#define HDIM 128
#define BHCNT 32
#define KDIM 2048
#define SCALE 0.08838834764831845f
#define LOGW 3.4657359027997265f
#define TAU 6e-3f
#define MAXWL 32768

__device__ __forceinline__ f32x4 mfma16(f16x8 a, f16x8 b, f32x4 c){
  return __builtin_amdgcn_mfma_f32_16x16x32_f16(a, b, c, 0, 0, 0);
}

__device__ __forceinline__ void g2l16(const f16* g, f16* l){
  __builtin_amdgcn_global_load_lds(
      (const __attribute__((address_space(1))) void*)g,
      (__attribute__((address_space(3))) void*)l, 16, 0, 0);
}

// ---------- prep: x -> hi/lo fp16 ----------
__global__ __launch_bounds__(256) void split_x_k(const float* __restrict__ x,
                                                 f16* __restrict__ xh, f16* __restrict__ xl){
  size_t i = ((size_t)blockIdx.x * 256 + threadIdx.x) * 4;
  float4 v = *(const float4*)(x + i);
  f16 h0 = (f16)v.x, h1 = (f16)v.y, h2 = (f16)v.z, h3 = (f16)v.w;
  union { f16 h[4]; ushort4 u; } a, b;
  a.h[0]=h0; a.h[1]=h1; a.h[2]=h2; a.h[3]=h3;
  b.h[0]=(f16)(v.x-(float)h0); b.h[1]=(f16)(v.y-(float)h1);
  b.h[2]=(f16)(v.z-(float)h2); b.h[3]=(f16)(v.w-(float)h3);
  *(ushort4*)(xh + i) = a.u;
  *(ushort4*)(xl + i) = b.u;
}

// ---------- prep: transpose+convert weights (in [Kd][Nd] -> out [Nd][Kd]) ----------
__global__ void transpose_k(const float* __restrict__ in, f16* __restrict__ ohi,
                            f16* __restrict__ olo, int Kd, int Nd, int NLO){
  __shared__ float t[32][33];
  int tx = threadIdx.x, ty = threadIdx.y;
  int n0 = blockIdx.x*32, k0 = blockIdx.y*32;
  #pragma unroll
  for (int i=0;i<4;i++) t[ty+i*8][tx] = in[(size_t)(k0+ty+i*8)*Nd + n0+tx];
  __syncthreads();
  #pragma unroll
  for (int i=0;i<4;i++){
    int n = n0 + ty + i*8, k = k0 + tx;
    float v = t[tx][ty+i*8];
    f16 h = (f16)v;
    ohi[(size_t)n*Kd + k] = h;
    if (n < NLO) olo[(size_t)n*Kd + k] = (f16)(v - (float)h);
  }
}

// ---------- prep: rope cos/sin table ----------
// numpy-exact: inv = f32_div(1.0f, f32(10000^e)) (two f32 roundings), angle = f32(s)*inv.
__global__ __launch_bounds__(256) void rope_table_k(float* __restrict__ ct, float* __restrict__ st){
  int i = blockIdx.x * 256 + threadIdx.x;
  int s = i >> 6, d = i & 63;
  float p32 = (float)pow(10000.0, (double)d / 64.0);
  float inv = __fdiv_rn(1.0f, p32);
  float f = __fmul_rn((float)s, inv);
  double a = (double)f;
  ct[i] = (float)cos(a);
  st[i] = (float)sin(a);
}

__global__ void zero_k(int* p){ *p = 0; }

// ---------- diagnostic: only fires if flagging machinery is broken ----------
__global__ void diag_k(const int* __restrict__ wcnt, float* __restrict__ out){
  int c = *wcnt;
  if (c == 0 || c >= MAXWL) out[0] = 1.0e9f + (float)c;
}

// ---------- GEMM: A[M][K] * Bt[N][K]^T. MODE 0: fp32 row-major out. 1: q/k fp32 strided. 2: v f16 strided ----------
template<int SPLIT, int MODE>
__global__ __launch_bounds__(256) void gemm_k(
    const f16* __restrict__ A, const f16* __restrict__ Al,
    const f16* __restrict__ Bt, const f16* __restrict__ Btl,
    float* __restrict__ o0, float* __restrict__ o1, f16* __restrict__ oh, int N){
  __shared__ f16 sm[SPLIT ? 16384 : 8192];
  const int tid = threadIdx.x, lane = tid & 63, wave = tid >> 6;
  const int wr = wave >> 1, wc = wave & 1;
  const int brow = blockIdx.y, bcol = blockIdx.x;
  f32x4 acc[4][4];
  #pragma unroll
  for (int m=0;m<4;m++)
    #pragma unroll
    for (int n=0;n<4;n++) acc[m][n] = (f32x4){0.f,0.f,0.f,0.f};
  const int srow = tid >> 2, scol = (tid & 3) * 8;
  const f16* ga0 = A  + (size_t)(brow*128 + srow)*KDIM + scol;
  const f16* gb0 = Bt + (size_t)(bcol*128 + srow)*KDIM + scol;
  f16* As = sm; f16* Bs = sm + 4096;
  f16* dA0 = As + wave*512; f16* dA1 = As + 2048 + wave*512;
  f16* dB0 = Bs + wave*512; f16* dB1 = Bs + 2048 + wave*512;
  const int aoff = (wr*64 + (lane & 15))*32 + (lane>>4)*8;
  const int boff = (wc*64 + (lane & 15))*32 + (lane>>4)*8;
  for (int kt = 0; kt < KDIM/32; ++kt){
    const size_t ko = (size_t)kt * 32;
    g2l16(ga0 + ko, dA0); g2l16(ga0 + (size_t)64*KDIM + ko, dA1);
    g2l16(gb0 + ko, dB0); g2l16(gb0 + (size_t)64*KDIM + ko, dB1);
    if constexpr (SPLIT){
      const f16* gal = Al  + (ga0 - A);
      const f16* gbl = Btl + (gb0 - Bt);
      g2l16(gal + ko, sm + 8192  + wave*512); g2l16(gal + (size_t)64*KDIM + ko, sm + 8192  + 2048 + wave*512);
      g2l16(gbl + ko, sm + 12288 + wave*512); g2l16(gbl + (size_t)64*KDIM + ko, sm + 12288 + 2048 + wave*512);
    }
    __syncthreads();
    f16x8 af[4], afl[4];
    #pragma unroll
    for (int m=0;m<4;m++){
      af[m] = *(const f16x8*)&As[aoff + m*16*32];
      if constexpr (SPLIT) afl[m] = *(const f16x8*)&sm[8192 + aoff + m*16*32];
    }
    #pragma unroll
    for (int n=0;n<4;n++){
      f16x8 bf = *(const f16x8*)&Bs[boff + n*16*32];
      f16x8 bfl;
      if constexpr (SPLIT) bfl = *(const f16x8*)&sm[12288 + boff + n*16*32];
      #pragma unroll
      for (int m=0;m<4;m++){
        acc[m][n] = mfma16(af[m], bf, acc[m][n]);
        if constexpr (SPLIT){
          acc[m][n] = mfma16(af[m],  bfl, acc[m][n]);
          acc[m][n] = mfma16(afl[m], bf,  acc[m][n]);
        }
      }
    }
    __syncthreads();
  }
  const int g = lane >> 4, q_ = lane & 15;
  #pragma unroll
  for (int m=0;m<4;m++)
    #pragma unroll
    for (int n=0;n<4;n++)
      #pragma unroll
      for (int j=0;j<4;j++){
        int row = brow*128 + wr*64 + m*16 + g*4 + j;
        int col = bcol*128 + wc*64 + n*16 + q_;
        float v = acc[m][n][j];
        if constexpr (MODE == 0){
          o0[(size_t)row * N + col] = v;
        } else if constexpr (MODE == 1){
          int b = row >> 13, s = row & 8191;
          int cl = col & 2047;
          int h = cl >> 7, hd = cl & 127;
          float* dst = (col < 2048) ? o0 : o1;
          dst[(((size_t)b*NH + h)*SEQ + s)*HDIM + hd] = v;
        } else {
          int b = row >> 13, s = row & 8191;
          int h = col >> 7, hd = col & 127;
          oh[(((size_t)b*NH + h)*SEQ + s)*HDIM + hd] = (f16)v;
        }
      }
}

// ---------- rope (fp32, in-place f16 overwrite) + LSH hash + near-zero flagging ----------
__global__ __launch_bounds__(256) void rope_hash_k(float* __restrict__ qk, const float* __restrict__ ct,
    const float* __restrict__ st, const float* __restrict__ proj, int* __restrict__ hout,
    int tag, int* __restrict__ wl, int* __restrict__ wcnt){
  const int lane = threadIdx.x & 63, wave = threadIdx.x >> 6;
  const int s = blockIdx.x * 4 + wave, bh = blockIdx.y;
  float* row = qk + ((size_t)bh * SEQ + s) * HDIM;
  float2 v = *(const float2*)(row + 2*lane);
  float ox = __shfl_xor(v.x, 32), oy = __shfl_xor(v.y, 32);
  const int dl = 2*lane, di = dl & 63;
  const float* cb = ct + (size_t)s*64; const float* sb = st + (size_t)s*64;
  float c0 = cb[di], c1 = cb[di+1], sn0 = sb[di], sn1 = sb[di+1];
  float r0, r1;
  if (lane < 32){ r0 = v.x*c0 - ox*sn0; r1 = v.y*c1 - oy*sn1; }
  else          { r0 = v.x*c0 + ox*sn0; r1 = v.y*c1 + oy*sn1; }
  union { f16 h[2]; u32 u; } pk;
  pk.h[0] = (f16)r0; pk.h[1] = (f16)r1;
  *(u32*)((f16*)row + dl) = pk.u;   // in-place: 128 f16 in first 256B of the 512B row
  float part[7];
  #pragma unroll
  for (int p=0;p<7;p++) part[p] = r0*proj[dl*7+p] + r1*proj[(dl+1)*7+p];
  #pragma unroll
  for (int off=32; off>=1; off>>=1){
    #pragma unroll
    for (int p=0;p<7;p++) part[p] += __shfl_xor(part[p], off);
  }
  if (lane == 0){
    int hs = 0; float mn = 1e30f;
    #pragma unroll
    for (int p=0;p<7;p++){ if (part[p] > 0.f) hs |= (1<<p); mn = fminf(mn, fabsf(part[p])); }
    hout[bh*SEQ + s] = hs;
    if (mn < TAU){
      int w = atomicAdd(wcnt, 1);
      if (w < MAXWL){ wl[2*w] = (bh<<1) | tag; wl[2*w+1] = s; }
    }
  }
}

// ---------- exact-f64 GEMM hash recompute for flagged rows, using the corrected f32 table ----------
__global__ __launch_bounds__(256) void fixup_k(const float* __restrict__ x, const float* __restrict__ w_in,
    const float* __restrict__ proj, const float* __restrict__ ct, const float* __restrict__ st,
    const int* __restrict__ wl, const int* __restrict__ wcnt,
    int* __restrict__ hq, int* __restrict__ hk){
  const int lane = threadIdx.x & 63, wave = threadIdx.x >> 6;
  const int gw = blockIdx.x * 4 + wave, nw = gridDim.x * 4;
  int count = *wcnt; if (count > MAXWL) count = MAXWL;
  for (int e = gw; e < count; e += nw){
    int tagbh = wl[2*e], s = wl[2*e+1];
    int tag = tagbh & 1, bh = tagbh >> 1;
    int b = bh >> 4, h = bh & 15;
    const float* xr = x + ((size_t)b*SEQ + s)*KDIM;
    const int c0i = tag*2048 + h*128 + lane;
    double a0 = 0.0, a1 = 0.0;
    for (int j = 0; j < KDIM; ++j){
      double xv = (double)xr[j];
      a0 += xv * (double)w_in[(size_t)j*6144 + c0i];
      a1 += xv * (double)w_in[(size_t)j*6144 + c0i + 64];
    }
    double c = (double)ct[(size_t)s*64 + lane];
    double sn = (double)st[(size_t)s*64 + lane];
    double r0 = a0*c - a1*sn;
    double r1 = a1*c + a0*sn;
    int hs = 0;
    #pragma unroll
    for (int p = 0; p < 7; ++p){
      double part = r0 * (double)proj[lane*7+p] + r1 * (double)proj[(lane+64)*7+p];
      #pragma unroll
      for (int off = 32; off >= 1; off >>= 1) part += __shfl_xor(part, off);
      if (part > 0.0) hs |= (1<<p);
    }
    if (lane == 0) (tag ? hk : hq)[bh*SEQ + s] = hs;
  }
}

// ---------- stable counting sort by hash (128 bins), one block per (b,h) ----------
__global__ __launch_bounds__(128) void sort_k(const int* __restrict__ hsh, int* __restrict__ idx){
  const int bh = blockIdx.x, tid = threadIdx.x;
  __shared__ unsigned char hl[SEQ];
  __shared__ int cnt[129];
  const int* hrow = hsh + bh*SEQ;
  for (int i = tid; i < SEQ; i += 128) hl[i] = (unsigned char)hrow[i];
  __syncthreads();
  int c = 0;
  for (int i = 0; i < SEQ; ++i) c += (hl[i] == tid) ? 1 : 0;
  cnt[tid+1] = c;
  __syncthreads();
  if (tid == 0){
    cnt[0] = 0;
    for (int v2 = 1; v2 <= 128; ++v2) cnt[v2] += cnt[v2-1];
  }
  __syncthreads();
  int pos = cnt[tid];
  int* orow = idx + bh*SEQ;
  for (int i = 0; i < SEQ; ++i) if (hl[i] == tid) orow[pos++] = i;
}

// ---------- fused block + sampled attention (single online softmax), scatter-unsort output ----------
__global__ __launch_bounds__(256) void attn_k(const f16* __restrict__ qr, const f16* __restrict__ kr,
    const f16* __restrict__ v, const int* __restrict__ qidx, const int* __restrict__ kidx,
    const int* __restrict__ smp, f16* __restrict__ out){
  const int tid = threadIdx.x, lane = tid & 63, wave = tid >> 6;
  const int chunk = blockIdx.x, bh = blockIdx.y;
  const int b = bh >> 4, h = bh & 15;
  const int qblock = chunk >> 2;
  __shared__ f16 Kl[32*136];
  __shared__ f16 Vt[128*40];
  __shared__ float biasl[32];
  const int g = lane >> 4, q_ = lane & 15;
  const int qpos = chunk*64 + wave*16 + q_;
  const int qi = qidx[bh*SEQ + qpos];
  const f16* qb = qr + ((size_t)bh*SEQ + qi)*256;   // row stride 256 f16 (in-place layout)
  f16x8 qf[4];
  #pragma unroll
  for (int c=0;c<4;c++) qf[c] = *(const f16x8*)(qb + c*32 + g*8);
  f32x4 O[8];
  #pragma unroll
  for (int c=0;c<8;c++) O[c] = (f32x4){0.f,0.f,0.f,0.f};
  float m_run = -1e30f, l_run = 0.f;
  for (int t = 0; t < 16; ++t){
    { // stage K tile [32][128] (pad stride 136)
      int kk = tid >> 3, seg = tid & 7;
      int kpos = (t < 8) ? (qblock*256 + t*32 + kk) : smp[bh*256 + (t-8)*32 + kk];
      int krw = kidx[bh*SEQ + kpos];
      const f16* ks = kr + ((size_t)bh*SEQ + krw)*256 + seg*16;
      *(f16x8*)&Kl[kk*136 + seg*16]     = *(const f16x8*)ks;
      *(f16x8*)&Kl[kk*136 + seg*16 + 8] = *(const f16x8*)(ks + 8);
    }
    { // stage V transposed [128][32] (pad stride 40)
      int kk = tid & 31, dseg = tid >> 5;
      int kpos = (t < 8) ? (qblock*256 + t*32 + kk) : smp[bh*256 + (t-8)*32 + kk];
      int vrw = kidx[bh*SEQ + kpos];
      const f16* vs = v + ((size_t)bh*SEQ + vrw)*HDIM + dseg*16;
      f16x8 va = *(const f16x8*)vs;
      f16x8 vb = *(const f16x8*)(vs + 8);
      #pragma unroll
      for (int i=0;i<8;i++) Vt[(dseg*16+i)*40 + kk] = va[i];
      #pragma unroll
      for (int i=0;i<8;i++) Vt[(dseg*16+8+i)*40 + kk] = vb[i];
    }
    if (tid < 32){
      float bv = 0.f;
      if (t >= 8){
        int spos = smp[bh*256 + (t-8)*32 + tid];
        bv = ((spos >> 8) == qblock) ? -1e30f : LOGW;
      }
      biasl[tid] = bv;
    }
    __syncthreads();
    // scores: C[key][q] = mfma(K, Q)
    f32x4 c0 = (f32x4){0.f,0.f,0.f,0.f}, c1 = (f32x4){0.f,0.f,0.f,0.f};
    #pragma unroll
    for (int c=0;c<4;c++){
      f16x8 k0 = *(const f16x8*)&Kl[q_*136 + c*32 + g*8];
      f16x8 k1 = *(const f16x8*)&Kl[(16+q_)*136 + c*32 + g*8];
      c0 = mfma16(k0, qf[c], c0);
      c1 = mfma16(k1, qf[c], c1);
    }
    float sc[8];
    #pragma unroll
    for (int j=0;j<4;j++){ sc[j] = c0[j]*SCALE + biasl[g*4+j]; sc[4+j] = c1[j]*SCALE + biasl[16+g*4+j]; }
    float mx = sc[0];
    #pragma unroll
    for (int i=1;i<8;i++) mx = fmaxf(mx, sc[i]);
    mx = fmaxf(mx, __shfl_xor(mx, 16));
    mx = fmaxf(mx, __shfl_xor(mx, 32));
    float mnew = fmaxf(m_run, mx);
    float al = __expf(m_run - mnew);
    float p[8]; float ps = 0.f;
    #pragma unroll
    for (int i=0;i<8;i++){ p[i] = __expf(sc[i] - mnew); ps += p[i]; }
    ps += __shfl_xor(ps, 16);
    ps += __shfl_xor(ps, 32);
    l_run = l_run * al + ps;
    m_run = mnew;
    float aj0 = __shfl(al, g*4+0), aj1 = __shfl(al, g*4+1);
    float aj2 = __shfl(al, g*4+2), aj3 = __shfl(al, g*4+3);
    #pragma unroll
    for (int c=0;c<8;c++){ O[c][0]*=aj0; O[c][1]*=aj1; O[c][2]*=aj2; O[c][3]*=aj3; }
    // pack P to f16 and redistribute C-layout -> A-frag layout (8 shfl)
    union { f16 h[2]; u32 u; } pk;
    pk.h[0]=(f16)p[0]; pk.h[1]=(f16)p[1]; u32 A0 = pk.u;
    pk.h[0]=(f16)p[2]; pk.h[1]=(f16)p[3]; u32 A1 = pk.u;
    pk.h[0]=(f16)p[4]; pk.h[1]=(f16)p[5]; u32 B0 = pk.u;
    pk.h[0]=(f16)p[6]; pk.h[1]=(f16)p[7]; u32 B1 = pk.u;
    int srcA = (((2*g)&3)<<4) | q_;
    int srcB = ((((2*g)+1)&3)<<4) | q_;
    bool selh = g >= 2;
    u32 xa0 = __shfl(A0, srcA), xb0 = __shfl(B0, srcA);
    u32 xa1 = __shfl(A1, srcA), xb1 = __shfl(B1, srcA);
    u32 xa2 = __shfl(A0, srcB), xb2 = __shfl(B0, srcB);
    u32 xa3 = __shfl(A1, srcB), xb3 = __shfl(B1, srcB);
    union { u32 w[4]; f16x8 f; } pf;
    pf.w[0] = selh ? xb0 : xa0;
    pf.w[1] = selh ? xb1 : xa1;
    pf.w[2] = selh ? xb2 : xa2;
    pf.w[3] = selh ? xb3 : xa3;
    #pragma unroll
    for (int c=0;c<8;c++){
      f16x8 vf = *(const f16x8*)&Vt[(c*16 + q_)*40 + g*8];
      O[c] = mfma16(pf.f, vf, O[c]);
    }
    __syncthreads();
  }
  float li0 = 1.f/__shfl(l_run, g*4+0), li1 = 1.f/__shfl(l_run, g*4+1);
  float li2 = 1.f/__shfl(l_run, g*4+2), li3 = 1.f/__shfl(l_run, g*4+3);
  const int posbase = chunk*64 + wave*16;
  #pragma unroll
  for (int j=0;j<4;j++){
    float li = (j==0)?li0:((j==1)?li1:((j==2)?li2:li3));
    int sorig = qidx[bh*SEQ + posbase + g*4 + j];
    f16* dst = out + (((size_t)b*SEQ + sorig)*NH + h)*HDIM;
    #pragma unroll
    for (int c=0;c<8;c++) dst[c*16 + q_] = (f16)(O[c][j] * li);
  }
}

extern "C" void kernel_launch(void* const* d_in, const int* in_sizes, int n_in,
                              void* d_out, int out_size, void* d_ws, size_t ws_size,
                              hipStream_t stream) {
  (void)in_sizes; (void)n_in; (void)out_size; (void)ws_size;
  const float* x     = (const float*)d_in[0];
  const float* w_in  = (const float*)d_in[1];
  const float* w_out = (const float*)d_in[2];
  const float* proj  = (const float*)d_in[3];
  const int*   smp   = (const int*)d_in[4];
  float* out = (float*)d_out;

  char* ws = (char*)d_ws;
  size_t off = 0;
  auto alloc = [&](size_t bytes){ void* p = ws + off; off += (bytes + 255) & ~(size_t)255; return p; };
  f16*   xh   = (f16*)alloc((size_t)16384*2048*2);
  f16*   xl   = (f16*)alloc((size_t)16384*2048*2);
  f16*   wh   = (f16*)alloc((size_t)6144*2048*2);
  f16*   wl   = (f16*)alloc((size_t)4096*2048*2);
  f16*   wo   = (f16*)alloc((size_t)2048*2048*2);
  float* qf   = (float*)alloc((size_t)BHCNT*SEQ*HDIM*4);
  float* kf   = (float*)alloc((size_t)BHCNT*SEQ*HDIM*4);
  f16*   vv   = (f16*)alloc((size_t)BHCNT*SEQ*HDIM*2);
  float* cost = (float*)alloc((size_t)SEQ*64*4);
  float* sint = (float*)alloc((size_t)SEQ*64*4);
  int*   hq   = (int*)alloc((size_t)BHCNT*SEQ*4);
  int*   hk   = (int*)alloc((size_t)BHCNT*SEQ*4);
  int*   qidx = (int*)alloc((size_t)BHCNT*SEQ*4);
  int*   kidx = (int*)alloc((size_t)BHCNT*SEQ*4);
  int*   wlst = (int*)alloc((size_t)MAXWL*2*4);
  int*   wcnt = (int*)alloc(256);
  f16*   attn = xl;   // xl is dead after the split GEMM; reuse as attention output

  zero_k<<<1, 1, 0, stream>>>(wcnt);
  split_x_k<<<32768, 256, 0, stream>>>(x, xh, xl);
  transpose_k<<<dim3(192,64), dim3(32,8), 0, stream>>>(w_in, wh, wl, 2048, 6144, 4096);
  transpose_k<<<dim3(64,64),  dim3(32,8), 0, stream>>>(w_out, wo, nullptr, 2048, 2048, 0);
  rope_table_k<<<2048, 256, 0, stream>>>(cost, sint);

  gemm_k<1,1><<<dim3(32,128), 256, 0, stream>>>(xh, xl, wh, wl, qf, kf, nullptr, 4096);
  gemm_k<0,2><<<dim3(16,128), 256, 0, stream>>>(xh, nullptr, wh + (size_t)4096*2048, nullptr,
                                                nullptr, nullptr, vv, 2048);

  rope_hash_k<<<dim3(2048,32), 256, 0, stream>>>(qf, cost, sint, proj, hq, 0, wlst, wcnt);
  rope_hash_k<<<dim3(2048,32), 256, 0, stream>>>(kf, cost, sint, proj, hk, 1, wlst, wcnt);

  // exact-f64 recompute of near-zero hash decisions (corrected f32 table)
  fixup_k<<<512, 256, 0, stream>>>(x, w_in, proj, cost, sint, wlst, wcnt, hq, hk);

  sort_k<<<32, 128, 0, stream>>>(hq, qidx);
  sort_k<<<32, 128, 0, stream>>>(hk, kidx);

  attn_k<<<dim3(128,32), 256, 0, stream>>>((const f16*)qf, (const f16*)kf, vv,
                                           qidx, kidx, smp, attn);

  gemm_k<0,0><<<dim3(16,128), 256, 0, stream>>>(attn, nullptr, wo, nullptr,
                                                out, nullptr, nullptr, 2048);

  // nominal-silent diagnostic: fires only if the flagging machinery is broken
  diag_k<<<1, 1, 0, stream>>>(wcnt, out);
}